// Round 12
// baseline (256.796 us; speedup 1.0000x reference)
//
#include <hip/hip_runtime.h>

// SGConv: out = A_norm^2 (x @ W^T) + b, A_norm = D^-1/2 (A+I) D^-1/2.
// yhat = dinv (.) h stored bf16; hop: h'_d = dinv_d * (sum yhat_src + yhat_d).
// R21: determinism fix + R20 xw. R20's post-timing tripwire exposed a latent
// race present since R2: atomicAdd ordering in p1 (gbase) and p2ab (lcur)
// permutes col entries per replay -> fp32 sum order varies ~1e-7 -> f2bf RNE
// boundary flips (1 bf16 ulp) in y1hat -> amplified to 7e-2 at the output.
// Fix: CANONICALIZE col — p2ab insertion-sorts each row's segment by src
// index (one thread/row, mean 16 entries); sorted order is independent of
// all arrival races; duplicates are bit-identical. Output is now bit-exact
// per replay. xw keeps R20's 8nx8o tile (4 b128 per 64 FMA, LDS floor
// ~15.6us; initial verification of R20 passed, only the replay check broke).
// prop (R16 2-node/wave) and p1 (R2 counting sort) unchanged.

#define FIN 128
#define FOUT 64
#define BN 256
#define KC2 32

#define NBUK 392          // buckets of 256 nodes (node >> 8)
#define BSH  8
#define NGRP 8
#define NSEG (NBUK * NGRP)
#define CAP  1024         // per-(bucket,group) staging capacity (mean 510, +22σ)
#define SEGSH 10
#define EPB_MAX 3328
#define CAP2 4864         // per-bucket col capacity (mean 4096, +12σ)

typedef unsigned short ushort_t;
typedef unsigned int uint_t;

__device__ __forceinline__ ushort_t f2bf(float f) {           // RNE
    uint_t u = __float_as_uint(f);
    return (ushort_t)((u + 0x7fffu + ((u >> 16) & 1u)) >> 16);
}

// ---- p1: block-local counting sort into (bucket, grp) segments ------------

__global__ __launch_bounds__(512) void p1_sort_kernel(const int* __restrict__ ei,
                                                      int* __restrict__ bcur,
                                                      int* __restrict__ bbuf,
                                                      int e, int epb) {
    __shared__ int entryA[EPB_MAX];
    __shared__ int sortedC[EPB_MAX];
    __shared__ ushort_t bktA[EPB_MAX];
    __shared__ ushort_t bktS[EPB_MAX];
    __shared__ int hist[512];
    __shared__ int stmp[512];
    __shared__ int loff[512];
    __shared__ int cur[512];
    __shared__ int gbase[512];

    const int tid = threadIdx.x;
    const int grp = blockIdx.x & (NGRP - 1);
    const int base = blockIdx.x * epb;
    int m = e - base; if (m > epb) m = epb; if (m < 0) m = 0;

    hist[tid] = 0; cur[tid] = 0;
    __syncthreads();

    for (int i = tid; i < m; i += 512) {
        int s = ei[base + i];
        int d = ei[e + base + i];
        int b = d >> BSH;
        entryA[i] = ((d & 255) << 17) | s;    // src < 2^17
        bktA[i]   = (ushort_t)b;
        atomicAdd(&hist[b], 1);
    }
    __syncthreads();

    int v = hist[tid];
    stmp[tid] = v;
    __syncthreads();
    for (int off = 1; off < 512; off <<= 1) {
        int add = (tid >= off) ? stmp[tid - off] : 0;
        __syncthreads();
        stmp[tid] += add;
        __syncthreads();
    }
    loff[tid] = stmp[tid] - v;
    if (tid < NBUK && v > 0) gbase[tid] = atomicAdd(&bcur[(tid << 3) | grp], v);
    __syncthreads();

    for (int i = tid; i < m; i += 512) {
        int b = bktA[i];
        int r = atomicAdd(&cur[b], 1);
        int p = loff[b] + r;
        sortedC[p] = entryA[i];
        bktS[p]    = (ushort_t)b;
    }
    __syncthreads();

    for (int i = tid; i < m; i += 512) {
        int b   = bktS[i];
        int idx = gbase[b] + (i - loff[b]);
        if (idx < CAP)
            bbuf[(((b << 3) | grp) << SEGSH) + idx] = sortedC[i];
    }
}

// ---- p2ab: one block per bucket (256 nodes) -------------------------------
// Stage 8 segments; histogram; scan; write rowcnt+dinv; place srcs; then
// CANONICALIZE: per-row insertion sort by src index (kills all atomicAdd
// order nondeterminism before anything consumes col); stream out dense.

__global__ __launch_bounds__(512) void p2ab_kernel(const int* __restrict__ bcur,
                                                   const int* __restrict__ bbuf,
                                                   int2* __restrict__ rowcnt,
                                                   float* __restrict__ dinv,
                                                   int* __restrict__ col, int n) {
    __shared__ int ebuf[CAP2];     // 19 KB staged entries
    __shared__ int tile[CAP2];     // 19 KB placed srcs
    __shared__ int lc[256];
    __shared__ int scn[256];
    __shared__ int lcur[256];
    __shared__ int segoff[NGRP + 1];

    const int b = blockIdx.x, tid = threadIdx.x;
    if (tid < 256) lc[tid] = 0;
    if (tid == 0) {
        int acc = 0;
        for (int g = 0; g < NGRP; ++g) {
            segoff[g] = acc;
            int mc = bcur[(b << 3) | g]; if (mc > CAP) mc = CAP;
            acc += mc;
        }
        segoff[NGRP] = acc;
    }
    __syncthreads();
    int me = segoff[NGRP]; if (me > CAP2) me = CAP2;

    for (int g = 0; g < NGRP; ++g) {
        int s0 = segoff[g], sz = segoff[g + 1] - s0;
        const int* p = bbuf + ((size_t)((b << 3) | g) << SEGSH);
        for (int i = tid; i < sz; i += 512)
            if (s0 + i < CAP2) ebuf[s0 + i] = p[i];
    }
    __syncthreads();

    for (int i = tid; i < me; i += 512)
        atomicAdd(&lc[(ebuf[i] >> 17) & 255], 1);
    __syncthreads();

    int v = 0, excl = 0;
    if (tid < 256) {
        v = lc[tid];
        scn[tid] = v;
    }
    __syncthreads();
    for (int off = 1; off < 256; off <<= 1) {
        int add = 0;
        if (tid < 256 && tid >= off) add = scn[tid - off];
        __syncthreads();
        if (tid < 256) scn[tid] += add;
        __syncthreads();
    }
    if (tid < 256) {
        excl = scn[tid] - v;
        int node = (b << BSH) + tid;
        if (node < n) {
            int2 rc; rc.x = b * CAP2 + excl; rc.y = v;
            rowcnt[node] = rc;
            dinv[node]   = rsqrtf((float)(v + 1));
        }
        lcur[tid] = excl;
    }
    __syncthreads();

    for (int i = tid; i < me; i += 512) {
        int ent = ebuf[i];
        int dl  = (ent >> 17) & 255;
        int pos = atomicAdd(&lcur[dl], 1);
        if (pos < CAP2) tile[pos] = ent & 0x1FFFF;
    }
    __syncthreads();

    // canonical per-row order: insertion sort row [excl, excl+v) by src
    if (tid < 256 && v > 1) {
        int s0 = excl;
        int cnt = v; if (s0 + cnt > CAP2) cnt = CAP2 - s0;
        for (int i = 1; i < cnt; ++i) {
            int key = tile[s0 + i];
            int j = i - 1;
            while (j >= 0 && tile[s0 + j] > key) {
                tile[s0 + j + 1] = tile[s0 + j];
                --j;
            }
            tile[s0 + j + 1] = key;
        }
    }
    __syncthreads();

    int used = scn[255]; if (used > CAP2) used = CAP2;
    for (int i = tid; i < used; i += 512)
        col[b * CAP2 + i] = tile[i];
}

// ---- y0hat = dinv (.) (x @ W^T) : blocked SGEMM, 8n x 8o thread tile ------
// Block 256 thr, 256 nodes. Thread (n32=tid>>3, o8=tid&7) owns nodes
// 8*n32..+7 x outs 8*o8..+7 (acc 16 float4 = 64 VGPR). Per panel p (K=32):
// x transposed with XOR group swizzle over 32 groups (write/read 2-way =
// free), W o-fast. Inner k: 2 x-b128 + 2 W-b128 broadcasts per 64 FMA.
// LDS 32 + 8.7 KB -> 3 blocks/CU.

__global__ __launch_bounds__(256) void xw_kernel(const float* __restrict__ x,
                                                 const float* __restrict__ W,
                                                 const float* __restrict__ dinv,
                                                 ushort_t* __restrict__ y, int n) {
    __shared__ float xsf[KC2 * BN];     // 32 KB
    __shared__ float wsf[KC2 * 68];     // 8.7 KB

    const int tid   = threadIdx.x;
    const int node0 = blockIdx.x * BN;
    const int n32 = tid >> 3;           // node group 0..31
    const int o8  = tid & 7;            // out group 0..7

    float4 a[8][2];
#pragma unroll
    for (int i = 0; i < 8; ++i) {
        a[i][0] = make_float4(0.f, 0.f, 0.f, 0.f);
        a[i][1] = make_float4(0.f, 0.f, 0.f, 0.f);
    }

    for (int p = 0; p < FIN / KC2; ++p) {     // 4 panels of K=32
        __syncthreads();
        // stage x transposed: k4 = tid&7 (float4 col), nd = tid>>3 (+32*it)
        {
            int k4 = tid & 7;
            int nd = tid >> 3;
#pragma unroll
            for (int it = 0; it < 8; ++it, nd += 32) {
                int gn = node0 + nd; if (gn > n - 1) gn = n - 1;
                float4 v = *(const float4*)(x + (size_t)gn * FIN + p * KC2 + 4 * k4);
                int bas = ((((nd >> 3) ^ k4) & 31) << 3) | (nd & 7);   // swizzle
                xsf[(4 * k4 + 0) * BN + bas] = v.x;
                xsf[(4 * k4 + 1) * BN + bas] = v.y;
                xsf[(4 * k4 + 2) * BN + bas] = v.z;
                xsf[(4 * k4 + 3) * BN + bas] = v.w;
            }
        }
        // stage W: o = tid&63 lane-fast (2-way banks), k4w = (tid>>6) + 4*it
        {
            int o  = tid & 63;
            int ks = tid >> 6;
#pragma unroll
            for (int it = 0; it < 2; ++it) {
                int k4w = ks + 4 * it;
                float4 v = *(const float4*)(W + (size_t)o * FIN + p * KC2 + 4 * k4w);
                wsf[(4 * k4w + 0) * 68 + o] = v.x;
                wsf[(4 * k4w + 1) * 68 + o] = v.y;
                wsf[(4 * k4w + 2) * 68 + o] = v.z;
                wsf[(4 * k4w + 3) * 68 + o] = v.w;
            }
        }
        __syncthreads();
#pragma unroll 4
        for (int k = 0; k < KC2; ++k) {
            const float* xp = xsf + k * BN + (((n32 ^ (k >> 2)) & 31) << 3);
            float4 xa0 = *(const float4*)(xp);
            float4 xa1 = *(const float4*)(xp + 4);
            const float* wp = wsf + k * 68 + 8 * o8;
            float4 wb0 = *(const float4*)(wp);
            float4 wb1 = *(const float4*)(wp + 4);
            float xe[8] = {xa0.x, xa0.y, xa0.z, xa0.w, xa1.x, xa1.y, xa1.z, xa1.w};
#pragma unroll
            for (int i = 0; i < 8; ++i) {
                a[i][0].x += xe[i] * wb0.x;
                a[i][0].y += xe[i] * wb0.y;
                a[i][0].z += xe[i] * wb0.z;
                a[i][0].w += xe[i] * wb0.w;
                a[i][1].x += xe[i] * wb1.x;
                a[i][1].y += xe[i] * wb1.y;
                a[i][1].z += xe[i] * wb1.z;
                a[i][1].w += xe[i] * wb1.w;
            }
        }
    }
#pragma unroll
    for (int i = 0; i < 8; ++i) {
        int nd = node0 + 8 * n32 + i;
        if (nd < n) {
            float di = dinv[nd];
            ushort4 o0, o1;
            o0.x = f2bf(di * a[i][0].x); o0.y = f2bf(di * a[i][0].y);
            o0.z = f2bf(di * a[i][0].z); o0.w = f2bf(di * a[i][0].w);
            o1.x = f2bf(di * a[i][1].x); o1.y = f2bf(di * a[i][1].y);
            o1.z = f2bf(di * a[i][1].z); o1.w = f2bf(di * a[i][1].w);
            *(ushort4*)(y + (size_t)nd * FOUT + 8 * o8)     = o0;
            *(ushort4*)(y + (size_t)nd * FOUT + 8 * o8 + 4) = o1;
        }
    }
}

// ---- one propagation hop: TWO nodes per wave ------------------------------
// lane l: features 4*(l&15)..+3 of row-group l>>4, for both nodes 2w, 2w+1.

#define ACC4(A0,A1,A2,A3,v)                              \
    A0 += __uint_as_float((v).x << 16);                  \
    A1 += __uint_as_float((v).x & 0xFFFF0000u);          \
    A2 += __uint_as_float((v).y << 16);                  \
    A3 += __uint_as_float((v).y & 0xFFFF0000u);

__global__ __launch_bounds__(512) void prop_kernel(const ushort_t* __restrict__ yin,
                            const int2* __restrict__ rowcnt, const int* __restrict__ col,
                            const float* __restrict__ dinv, const float* __restrict__ bias,
                            ushort_t* __restrict__ yout_bf, float* __restrict__ yout_f,
                            int n, int mode) {
    int wv   = __builtin_amdgcn_readfirstlane((blockIdx.x * blockDim.x + threadIdx.x) >> 6);
    int lane = threadIdx.x & 63;
    const int widA = wv << 1;
    if (widA >= n) return;
    const int widB = widA + 1;
    const bool hasB = (widB < n);
    const int grp = lane >> 4;          // row-group 0..3
    const int fl  = (lane & 15) << 2;   // feature base

    int2 rcA = rowcnt[widA];
    int2 rcB = rowcnt[hasB ? widB : widA];
    const int degA = rcA.y;
    const int degB = hasB ? rcB.y : 0;

    float aA0=0.f,aA1=0.f,aA2=0.f,aA3=0.f;
    float aB0=0.f,aB1=0.f,aB2=0.f,aB3=0.f;
    if (grp == 0) {                     // self loops, counted once
        uint2 vA = *(const uint2*)(yin + (size_t)widA * FOUT + fl);
        ACC4(aA0,aA1,aA2,aA3,vA)
        if (hasB) {
            uint2 vB = *(const uint2*)(yin + (size_t)widB * FOUT + fl);
            ACC4(aB0,aB1,aB2,aB3,vB)
        }
    }

    int mxdeg = degA > degB ? degA : degB;
    for (int base = 0; base < mxdeg; base += 64) {
        int cnA = degA - base; cnA = cnA < 0 ? 0 : (cnA > 64 ? 64 : cnA);
        int cnB = degB - base; cnB = cnB < 0 ? 0 : (cnB > 64 ? 64 : cnB);
        int colvA = 0, colvB = 0;
        if (cnA > 0) colvA = col[rcA.x + base + (lane < cnA ? lane : cnA - 1)];
        if (cnB > 0) colvB = col[rcB.x + base + (lane < cnB ? lane : cnB - 1)];
        int mx = cnA > cnB ? cnA : cnB;
        for (int j = 0; j < mx; j += 16) {
            // issue up to 8 predicated independent gathers, then accumulate
            uint2 vA[4], vB[4];
#pragma unroll
            for (int u = 0; u < 4; ++u) {
                int r  = j + 4 * u + grp;
                int sA = __shfl(colvA, r < cnA ? r : 0);
                int sB = __shfl(colvB, r < cnB ? r : 0);
                vA[u] = make_uint2(0u, 0u);
                vB[u] = make_uint2(0u, 0u);
                if (r < cnA) vA[u] = *(const uint2*)(yin + (size_t)sA * FOUT + fl);
                if (r < cnB) vB[u] = *(const uint2*)(yin + (size_t)sB * FOUT + fl);
            }
#pragma unroll
            for (int u = 0; u < 4; ++u) {
                ACC4(aA0,aA1,aA2,aA3,vA[u])
                ACC4(aB0,aB1,aB2,aB3,vB[u])
            }
        }
    }

    // reduce the 4 row-groups: lanes {l, l^16, l^32, l^48}
    aA0 += __shfl_xor(aA0, 16); aA0 += __shfl_xor(aA0, 32);
    aA1 += __shfl_xor(aA1, 16); aA1 += __shfl_xor(aA1, 32);
    aA2 += __shfl_xor(aA2, 16); aA2 += __shfl_xor(aA2, 32);
    aA3 += __shfl_xor(aA3, 16); aA3 += __shfl_xor(aA3, 32);
    aB0 += __shfl_xor(aB0, 16); aB0 += __shfl_xor(aB0, 32);
    aB1 += __shfl_xor(aB1, 16); aB1 += __shfl_xor(aB1, 32);
    aB2 += __shfl_xor(aB2, 16); aB2 += __shfl_xor(aB2, 32);
    aB3 += __shfl_xor(aB3, 16); aB3 += __shfl_xor(aB3, 32);

    if (lane < 16) {
        float diA = dinv[widA];
        if (mode == 0) {
            float sc = diA * diA;
            ushort4 o;
            o.x = f2bf(sc * aA0); o.y = f2bf(sc * aA1);
            o.z = f2bf(sc * aA2); o.w = f2bf(sc * aA3);
            *(ushort4*)(yout_bf + (size_t)widA * FOUT + fl) = o;
            if (hasB) {
                float diB = dinv[widB], sb2 = diB * diB;
                ushort4 p;
                p.x = f2bf(sb2 * aB0); p.y = f2bf(sb2 * aB1);
                p.z = f2bf(sb2 * aB2); p.w = f2bf(sb2 * aB3);
                *(ushort4*)(yout_bf + (size_t)widB * FOUT + fl) = p;
            }
        } else {
            float4 bo;
            bo.x = bias[fl]; bo.y = bias[fl + 1];
            bo.z = bias[fl + 2]; bo.w = bias[fl + 3];
            float4 o;
            o.x = diA * aA0 + bo.x; o.y = diA * aA1 + bo.y;
            o.z = diA * aA2 + bo.z; o.w = diA * aA3 + bo.w;
            *(float4*)(yout_f + (size_t)widA * FOUT + fl) = o;
            if (hasB) {
                float diB = dinv[widB];
                float4 p;
                p.x = diB * aB0 + bo.x; p.y = diB * aB1 + bo.y;
                p.z = diB * aB2 + bo.z; p.w = diB * aB3 + bo.w;
                *(float4*)(yout_f + (size_t)widB * FOUT + fl) = p;
            }
        }
    }
}

// ---- launch ---------------------------------------------------------------

extern "C" void kernel_launch(void* const* d_in, const int* in_sizes, int n_in,
                              void* d_out, int out_size, void* d_ws, size_t ws_size,
                              hipStream_t stream) {
    const float* x  = (const float*)d_in[0];
    const int*   ei = (const int*)d_in[1];
    const float* W  = (const float*)d_in[2];
    const float* b  = (const float*)d_in[3];
    float* out = (float*)d_out;

    int n = in_sizes[0] / FIN;   // 100000
    int e = in_sizes[1] / 2;     // 1600000

    int P1B = (e + 3124) / 3125;             // 512
    int epb = (e + P1B - 1) / P1B;           // 3125 <= EPB_MAX

    char* w = (char*)d_ws;
    int*   bbuf   = (int*)w;      w += (size_t)NSEG * CAP * sizeof(int);      // 12.85 MB
    int*   col    = (int*)w;      w += (size_t)NBUK * CAP2 * sizeof(int);     // 7.63 MB
    ushort_t* y0b = (ushort_t*)w; w += (size_t)n * FOUT * sizeof(ushort_t);   // 12.8 MB
    ushort_t* y1b = (ushort_t*)w; w += (size_t)n * FOUT * sizeof(ushort_t);   // 12.8 MB
    int2*  rowcnt = (int2*)w;     w += (size_t)n * sizeof(int2);              // 0.8 MB
    int*   bcur   = (int*)w;      w += (size_t)NSEG * sizeof(int);
    float* dinv   = (float*)w;    w += (size_t)n * sizeof(float);

    (void)hipMemsetAsync(bcur, 0, (size_t)NSEG * sizeof(int), stream);
    p1_sort_kernel<<<P1B, 512, 0, stream>>>(ei, bcur, bbuf, e, epb);
    p2ab_kernel<<<NBUK, 512, 0, stream>>>(bcur, bbuf, rowcnt, dinv, col, n);

    xw_kernel<<<(n + BN - 1) / BN, 256, 0, stream>>>(x, W, dinv, y0b, n);

    int waves = (n + 1) / 2;
    int pb = (waves + 7) / 8;                // 8 waves per 512-thread block
    prop_kernel<<<pb, 512, 0, stream>>>(y0b, rowcnt, col, dinv, nullptr, y1b, nullptr, n, 0);
    prop_kernel<<<pb, 512, 0, stream>>>(y1b, rowcnt, col, dinv, b, nullptr, out, n, 1);
}

// Round 14
// 228.156 us; speedup vs baseline: 1.1255x; 1.1255x over previous
//
#include <hip/hip_runtime.h>

// SGConv: out = A_norm^2 (x @ W^T) + b, A_norm = D^-1/2 (A+I) D^-1/2.
// yhat = dinv (.) h stored bf16; hop: h'_d = dinv_d * (sum yhat_src + yhat_d).
// R22 (resubmit — round 13 was a broker timeout, kernel never measured):
// canonicalization rebuilt. R21's per-thread insertion sort cost 35us
// (p2ab 55.5us, 1.69M LDS conflicts, serial O(deg^2) chains). Replacement:
// parallel STABLE-RANK rewrite — placement stores full ent (dl<<17|src) in
// tile; each thread, per owned entry i, computes dst = s0 + #{tile[j]<ent}
// + #{j<i: tile[j]==ent} scanning its row (mean 16) and writes ent&0x1FFFF
// to ebuf[dst] (ebuf dead after placement). Bijection per row; equal values
// are bit-identical -> col content deterministic -> bit-exact replays.
// ~136 LDS reads/thread, parallel per entry, no serial tails.
// xw keeps R20 8nx8o tile; prop R16 2-node/wave; p1 R2 counting sort.

#define FIN 128
#define FOUT 64
#define BN 256
#define KC2 32

#define NBUK 392          // buckets of 256 nodes (node >> 8)
#define BSH  8
#define NGRP 8
#define NSEG (NBUK * NGRP)
#define CAP  1024         // per-(bucket,group) staging capacity (mean 510, +22σ)
#define SEGSH 10
#define EPB_MAX 3328
#define CAP2 4864         // per-bucket col capacity (mean 4096, +12σ)

typedef unsigned short ushort_t;
typedef unsigned int uint_t;

__device__ __forceinline__ ushort_t f2bf(float f) {           // RNE
    uint_t u = __float_as_uint(f);
    return (ushort_t)((u + 0x7fffu + ((u >> 16) & 1u)) >> 16);
}

// ---- p1: block-local counting sort into (bucket, grp) segments ------------

__global__ __launch_bounds__(512) void p1_sort_kernel(const int* __restrict__ ei,
                                                      int* __restrict__ bcur,
                                                      int* __restrict__ bbuf,
                                                      int e, int epb) {
    __shared__ int entryA[EPB_MAX];
    __shared__ int sortedC[EPB_MAX];
    __shared__ ushort_t bktA[EPB_MAX];
    __shared__ ushort_t bktS[EPB_MAX];
    __shared__ int hist[512];
    __shared__ int stmp[512];
    __shared__ int loff[512];
    __shared__ int cur[512];
    __shared__ int gbase[512];

    const int tid = threadIdx.x;
    const int grp = blockIdx.x & (NGRP - 1);
    const int base = blockIdx.x * epb;
    int m = e - base; if (m > epb) m = epb; if (m < 0) m = 0;

    hist[tid] = 0; cur[tid] = 0;
    __syncthreads();

    for (int i = tid; i < m; i += 512) {
        int s = ei[base + i];
        int d = ei[e + base + i];
        int b = d >> BSH;
        entryA[i] = ((d & 255) << 17) | s;    // src < 2^17
        bktA[i]   = (ushort_t)b;
        atomicAdd(&hist[b], 1);
    }
    __syncthreads();

    int v = hist[tid];
    stmp[tid] = v;
    __syncthreads();
    for (int off = 1; off < 512; off <<= 1) {
        int add = (tid >= off) ? stmp[tid - off] : 0;
        __syncthreads();
        stmp[tid] += add;
        __syncthreads();
    }
    loff[tid] = stmp[tid] - v;
    if (tid < NBUK && v > 0) gbase[tid] = atomicAdd(&bcur[(tid << 3) | grp], v);
    __syncthreads();

    for (int i = tid; i < m; i += 512) {
        int b = bktA[i];
        int r = atomicAdd(&cur[b], 1);
        int p = loff[b] + r;
        sortedC[p] = entryA[i];
        bktS[p]    = (ushort_t)b;
    }
    __syncthreads();

    for (int i = tid; i < m; i += 512) {
        int b   = bktS[i];
        int idx = gbase[b] + (i - loff[b]);
        if (idx < CAP)
            bbuf[(((b << 3) | grp) << SEGSH) + idx] = sortedC[i];
    }
}

// ---- p2ab: one block per bucket (256 nodes) -------------------------------
// Stage 8 segments; histogram; scan; write rowcnt+dinv; place FULL entries;
// canonical stable-rank rewrite into ebuf (parallel per entry); stream out.

__global__ __launch_bounds__(512) void p2ab_kernel(const int* __restrict__ bcur,
                                                   const int* __restrict__ bbuf,
                                                   int2* __restrict__ rowcnt,
                                                   float* __restrict__ dinv,
                                                   int* __restrict__ col, int n) {
    __shared__ int ebuf[CAP2];     // 19 KB staged entries -> sorted out buf
    __shared__ int tile[CAP2];     // 19 KB placed full entries
    __shared__ int lc[256];
    __shared__ int scn[256];
    __shared__ int lcur[256];
    __shared__ int segoff[NGRP + 1];

    const int b = blockIdx.x, tid = threadIdx.x;
    if (tid < 256) lc[tid] = 0;
    if (tid == 0) {
        int acc = 0;
        for (int g = 0; g < NGRP; ++g) {
            segoff[g] = acc;
            int mc = bcur[(b << 3) | g]; if (mc > CAP) mc = CAP;
            acc += mc;
        }
        segoff[NGRP] = acc;
    }
    __syncthreads();
    int me = segoff[NGRP]; if (me > CAP2) me = CAP2;

    for (int g = 0; g < NGRP; ++g) {
        int s0 = segoff[g], sz = segoff[g + 1] - s0;
        const int* p = bbuf + ((size_t)((b << 3) | g) << SEGSH);
        for (int i = tid; i < sz; i += 512)
            if (s0 + i < CAP2) ebuf[s0 + i] = p[i];
    }
    __syncthreads();

    for (int i = tid; i < me; i += 512)
        atomicAdd(&lc[(ebuf[i] >> 17) & 255], 1);
    __syncthreads();

    int v = 0, excl = 0;
    if (tid < 256) {
        v = lc[tid];
        scn[tid] = v;
    }
    __syncthreads();
    for (int off = 1; off < 256; off <<= 1) {
        int add = 0;
        if (tid < 256 && tid >= off) add = scn[tid - off];
        __syncthreads();
        if (tid < 256) scn[tid] += add;
        __syncthreads();
    }
    if (tid < 256) {
        excl = scn[tid] - v;
        int node = (b << BSH) + tid;
        if (node < n) {
            int2 rc; rc.x = b * CAP2 + excl; rc.y = v;
            rowcnt[node] = rc;
            dinv[node]   = rsqrtf((float)(v + 1));
        }
        lcur[tid] = excl;
    }
    __syncthreads();

    // place FULL entries (row bits kept: same-row compares == src compares)
    for (int i = tid; i < me; i += 512) {
        int ent = ebuf[i];
        int dl  = (ent >> 17) & 255;
        int pos = atomicAdd(&lcur[dl], 1);
        if (pos < CAP2) tile[pos] = ent;
    }
    __syncthreads();

    // canonical stable-rank rewrite: tile -> ebuf (sorted per row by value)
    int used = scn[255]; if (used > CAP2) used = CAP2;
    for (int i = tid; i < used; i += 512) {
        int ent = tile[i];
        int r   = (ent >> 17) & 255;
        int cnt = lc[r];
        int s0  = scn[r] - cnt;
        int hi  = s0 + cnt; if (hi > CAP2) hi = CAP2;
        int rk  = 0;
        for (int j = s0; j < hi; ++j) {
            int t = tile[j];
            rk += (t < ent) + ((t == ent) & (j < i));
        }
        int dst = s0 + rk;
        if (dst < CAP2) ebuf[dst] = ent & 0x1FFFF;
    }
    __syncthreads();

    for (int i = tid; i < used; i += 512)
        col[b * CAP2 + i] = ebuf[i];
}

// ---- y0hat = dinv (.) (x @ W^T) : blocked SGEMM, 8n x 8o thread tile ------
// Block 256 thr, 256 nodes. Thread (n32=tid>>3, o8=tid&7) owns nodes
// 8*n32..+7 x outs 8*o8..+7 (acc 16 float4 = 64 VGPR). Per panel p (K=32):
// x transposed with XOR group swizzle over 32 groups (write/read 2-way =
// free), W o-fast. Inner k: 2 x-b128 + 2 W-b128 broadcasts per 64 FMA.
// LDS 32 + 8.7 KB -> 3 blocks/CU.

__global__ __launch_bounds__(256) void xw_kernel(const float* __restrict__ x,
                                                 const float* __restrict__ W,
                                                 const float* __restrict__ dinv,
                                                 ushort_t* __restrict__ y, int n) {
    __shared__ float xsf[KC2 * BN];     // 32 KB
    __shared__ float wsf[KC2 * 68];     // 8.7 KB

    const int tid   = threadIdx.x;
    const int node0 = blockIdx.x * BN;
    const int n32 = tid >> 3;           // node group 0..31
    const int o8  = tid & 7;            // out group 0..7

    float4 a[8][2];
#pragma unroll
    for (int i = 0; i < 8; ++i) {
        a[i][0] = make_float4(0.f, 0.f, 0.f, 0.f);
        a[i][1] = make_float4(0.f, 0.f, 0.f, 0.f);
    }

    for (int p = 0; p < FIN / KC2; ++p) {     // 4 panels of K=32
        __syncthreads();
        // stage x transposed: k4 = tid&7 (float4 col), nd = tid>>3 (+32*it)
        {
            int k4 = tid & 7;
            int nd = tid >> 3;
#pragma unroll
            for (int it = 0; it < 8; ++it, nd += 32) {
                int gn = node0 + nd; if (gn > n - 1) gn = n - 1;
                float4 v = *(const float4*)(x + (size_t)gn * FIN + p * KC2 + 4 * k4);
                int bas = ((((nd >> 3) ^ k4) & 31) << 3) | (nd & 7);   // swizzle
                xsf[(4 * k4 + 0) * BN + bas] = v.x;
                xsf[(4 * k4 + 1) * BN + bas] = v.y;
                xsf[(4 * k4 + 2) * BN + bas] = v.z;
                xsf[(4 * k4 + 3) * BN + bas] = v.w;
            }
        }
        // stage W: o = tid&63 lane-fast (2-way banks), k4w = (tid>>6) + 4*it
        {
            int o  = tid & 63;
            int ks = tid >> 6;
#pragma unroll
            for (int it = 0; it < 2; ++it) {
                int k4w = ks + 4 * it;
                float4 v = *(const float4*)(W + (size_t)o * FIN + p * KC2 + 4 * k4w);
                wsf[(4 * k4w + 0) * 68 + o] = v.x;
                wsf[(4 * k4w + 1) * 68 + o] = v.y;
                wsf[(4 * k4w + 2) * 68 + o] = v.z;
                wsf[(4 * k4w + 3) * 68 + o] = v.w;
            }
        }
        __syncthreads();
#pragma unroll 4
        for (int k = 0; k < KC2; ++k) {
            const float* xp = xsf + k * BN + (((n32 ^ (k >> 2)) & 31) << 3);
            float4 xa0 = *(const float4*)(xp);
            float4 xa1 = *(const float4*)(xp + 4);
            const float* wp = wsf + k * 68 + 8 * o8;
            float4 wb0 = *(const float4*)(wp);
            float4 wb1 = *(const float4*)(wp + 4);
            float xe[8] = {xa0.x, xa0.y, xa0.z, xa0.w, xa1.x, xa1.y, xa1.z, xa1.w};
#pragma unroll
            for (int i = 0; i < 8; ++i) {
                a[i][0].x += xe[i] * wb0.x;
                a[i][0].y += xe[i] * wb0.y;
                a[i][0].z += xe[i] * wb0.z;
                a[i][0].w += xe[i] * wb0.w;
                a[i][1].x += xe[i] * wb1.x;
                a[i][1].y += xe[i] * wb1.y;
                a[i][1].z += xe[i] * wb1.z;
                a[i][1].w += xe[i] * wb1.w;
            }
        }
    }
#pragma unroll
    for (int i = 0; i < 8; ++i) {
        int nd = node0 + 8 * n32 + i;
        if (nd < n) {
            float di = dinv[nd];
            ushort4 o0, o1;
            o0.x = f2bf(di * a[i][0].x); o0.y = f2bf(di * a[i][0].y);
            o0.z = f2bf(di * a[i][0].z); o0.w = f2bf(di * a[i][0].w);
            o1.x = f2bf(di * a[i][1].x); o1.y = f2bf(di * a[i][1].y);
            o1.z = f2bf(di * a[i][1].z); o1.w = f2bf(di * a[i][1].w);
            *(ushort4*)(y + (size_t)nd * FOUT + 8 * o8)     = o0;
            *(ushort4*)(y + (size_t)nd * FOUT + 8 * o8 + 4) = o1;
        }
    }
}

// ---- one propagation hop: TWO nodes per wave ------------------------------
// lane l: features 4*(l&15)..+3 of row-group l>>4, for both nodes 2w, 2w+1.

#define ACC4(A0,A1,A2,A3,v)                              \
    A0 += __uint_as_float((v).x << 16);                  \
    A1 += __uint_as_float((v).x & 0xFFFF0000u);          \
    A2 += __uint_as_float((v).y << 16);                  \
    A3 += __uint_as_float((v).y & 0xFFFF0000u);

__global__ __launch_bounds__(512) void prop_kernel(const ushort_t* __restrict__ yin,
                            const int2* __restrict__ rowcnt, const int* __restrict__ col,
                            const float* __restrict__ dinv, const float* __restrict__ bias,
                            ushort_t* __restrict__ yout_bf, float* __restrict__ yout_f,
                            int n, int mode) {
    int wv   = __builtin_amdgcn_readfirstlane((blockIdx.x * blockDim.x + threadIdx.x) >> 6);
    int lane = threadIdx.x & 63;
    const int widA = wv << 1;
    if (widA >= n) return;
    const int widB = widA + 1;
    const bool hasB = (widB < n);
    const int grp = lane >> 4;          // row-group 0..3
    const int fl  = (lane & 15) << 2;   // feature base

    int2 rcA = rowcnt[widA];
    int2 rcB = rowcnt[hasB ? widB : widA];
    const int degA = rcA.y;
    const int degB = hasB ? rcB.y : 0;

    float aA0=0.f,aA1=0.f,aA2=0.f,aA3=0.f;
    float aB0=0.f,aB1=0.f,aB2=0.f,aB3=0.f;
    if (grp == 0) {                     // self loops, counted once
        uint2 vA = *(const uint2*)(yin + (size_t)widA * FOUT + fl);
        ACC4(aA0,aA1,aA2,aA3,vA)
        if (hasB) {
            uint2 vB = *(const uint2*)(yin + (size_t)widB * FOUT + fl);
            ACC4(aB0,aB1,aB2,aB3,vB)
        }
    }

    int mxdeg = degA > degB ? degA : degB;
    for (int base = 0; base < mxdeg; base += 64) {
        int cnA = degA - base; cnA = cnA < 0 ? 0 : (cnA > 64 ? 64 : cnA);
        int cnB = degB - base; cnB = cnB < 0 ? 0 : (cnB > 64 ? 64 : cnB);
        int colvA = 0, colvB = 0;
        if (cnA > 0) colvA = col[rcA.x + base + (lane < cnA ? lane : cnA - 1)];
        if (cnB > 0) colvB = col[rcB.x + base + (lane < cnB ? lane : cnB - 1)];
        int mx = cnA > cnB ? cnA : cnB;
        for (int j = 0; j < mx; j += 16) {
            // issue up to 8 predicated independent gathers, then accumulate
            uint2 vA[4], vB[4];
#pragma unroll
            for (int u = 0; u < 4; ++u) {
                int r  = j + 4 * u + grp;
                int sA = __shfl(colvA, r < cnA ? r : 0);
                int sB = __shfl(colvB, r < cnB ? r : 0);
                vA[u] = make_uint2(0u, 0u);
                vB[u] = make_uint2(0u, 0u);
                if (r < cnA) vA[u] = *(const uint2*)(yin + (size_t)sA * FOUT + fl);
                if (r < cnB) vB[u] = *(const uint2*)(yin + (size_t)sB * FOUT + fl);
            }
#pragma unroll
            for (int u = 0; u < 4; ++u) {
                ACC4(aA0,aA1,aA2,aA3,vA[u])
                ACC4(aB0,aB1,aB2,aB3,vB[u])
            }
        }
    }

    // reduce the 4 row-groups: lanes {l, l^16, l^32, l^48}
    aA0 += __shfl_xor(aA0, 16); aA0 += __shfl_xor(aA0, 32);
    aA1 += __shfl_xor(aA1, 16); aA1 += __shfl_xor(aA1, 32);
    aA2 += __shfl_xor(aA2, 16); aA2 += __shfl_xor(aA2, 32);
    aA3 += __shfl_xor(aA3, 16); aA3 += __shfl_xor(aA3, 32);
    aB0 += __shfl_xor(aB0, 16); aB0 += __shfl_xor(aB0, 32);
    aB1 += __shfl_xor(aB1, 16); aB1 += __shfl_xor(aB1, 32);
    aB2 += __shfl_xor(aB2, 16); aB2 += __shfl_xor(aB2, 32);
    aB3 += __shfl_xor(aB3, 16); aB3 += __shfl_xor(aB3, 32);

    if (lane < 16) {
        float diA = dinv[widA];
        if (mode == 0) {
            float sc = diA * diA;
            ushort4 o;
            o.x = f2bf(sc * aA0); o.y = f2bf(sc * aA1);
            o.z = f2bf(sc * aA2); o.w = f2bf(sc * aA3);
            *(ushort4*)(yout_bf + (size_t)widA * FOUT + fl) = o;
            if (hasB) {
                float diB = dinv[widB], sb2 = diB * diB;
                ushort4 p;
                p.x = f2bf(sb2 * aB0); p.y = f2bf(sb2 * aB1);
                p.z = f2bf(sb2 * aB2); p.w = f2bf(sb2 * aB3);
                *(ushort4*)(yout_bf + (size_t)widB * FOUT + fl) = p;
            }
        } else {
            float4 bo;
            bo.x = bias[fl]; bo.y = bias[fl + 1];
            bo.z = bias[fl + 2]; bo.w = bias[fl + 3];
            float4 o;
            o.x = diA * aA0 + bo.x; o.y = diA * aA1 + bo.y;
            o.z = diA * aA2 + bo.z; o.w = diA * aA3 + bo.w;
            *(float4*)(yout_f + (size_t)widA * FOUT + fl) = o;
            if (hasB) {
                float diB = dinv[widB];
                float4 p;
                p.x = diB * aB0 + bo.x; p.y = diB * aB1 + bo.y;
                p.z = diB * aB2 + bo.z; p.w = diB * aB3 + bo.w;
                *(float4*)(yout_f + (size_t)widB * FOUT + fl) = p;
            }
        }
    }
}

// ---- launch ---------------------------------------------------------------

extern "C" void kernel_launch(void* const* d_in, const int* in_sizes, int n_in,
                              void* d_out, int out_size, void* d_ws, size_t ws_size,
                              hipStream_t stream) {
    const float* x  = (const float*)d_in[0];
    const int*   ei = (const int*)d_in[1];
    const float* W  = (const float*)d_in[2];
    const float* b  = (const float*)d_in[3];
    float* out = (float*)d_out;

    int n = in_sizes[0] / FIN;   // 100000
    int e = in_sizes[1] / 2;     // 1600000

    int P1B = (e + 3124) / 3125;             // 512
    int epb = (e + P1B - 1) / P1B;           // 3125 <= EPB_MAX

    char* w = (char*)d_ws;
    int*   bbuf   = (int*)w;      w += (size_t)NSEG * CAP * sizeof(int);      // 12.85 MB
    int*   col    = (int*)w;      w += (size_t)NBUK * CAP2 * sizeof(int);     // 7.63 MB
    ushort_t* y0b = (ushort_t*)w; w += (size_t)n * FOUT * sizeof(ushort_t);   // 12.8 MB
    ushort_t* y1b = (ushort_t*)w; w += (size_t)n * FOUT * sizeof(ushort_t);   // 12.8 MB
    int2*  rowcnt = (int2*)w;     w += (size_t)n * sizeof(int2);              // 0.8 MB
    int*   bcur   = (int*)w;      w += (size_t)NSEG * sizeof(int);
    float* dinv   = (float*)w;    w += (size_t)n * sizeof(float);

    (void)hipMemsetAsync(bcur, 0, (size_t)NSEG * sizeof(int), stream);
    p1_sort_kernel<<<P1B, 512, 0, stream>>>(ei, bcur, bbuf, e, epb);
    p2ab_kernel<<<NBUK, 512, 0, stream>>>(bcur, bbuf, rowcnt, dinv, col, n);

    xw_kernel<<<(n + BN - 1) / BN, 256, 0, stream>>>(x, W, dinv, y0b, n);

    int waves = (n + 1) / 2;
    int pb = (waves + 7) / 8;                // 8 waves per 512-thread block
    prop_kernel<<<pb, 512, 0, stream>>>(y0b, rowcnt, col, dinv, nullptr, y1b, nullptr, n, 0);
    prop_kernel<<<pb, 512, 0, stream>>>(y1b, rowcnt, col, dinv, b, nullptr, out, n, 1);
}